// Round 1
// baseline (425.047 us; speedup 1.0000x reference)
//
#include <hip/hip_runtime.h>
#include <hip/hip_bf16.h>

typedef float f32x4 __attribute__((ext_vector_type(4)));
typedef short s16x8 __attribute__((ext_vector_type(8)));

__device__ __forceinline__ short f2bf(float f) {
    union { float f; unsigned int u; } c; c.f = f;
    unsigned int u = c.u;
    u += 0x7FFFu + ((u >> 16) & 1u);          // round-to-nearest-even
    return (short)(u >> 16);
}

// ---------------- weight packing: MFMA B-fragment order ----------------
// out[((ks*nbTot + nb)*64 + lane)*8 + j] = bf16( W[(ks*32 + (lane>>4)*8 + j)][nb*16 + (lane&15)] )
__global__ void pack_w(const float* __restrict__ W, short* __restrict__ out,
                       int Kreal, int N, int nbTot, int total) {
    int tid = blockIdx.x * 256 + threadIdx.x;
    if (tid >= total) return;
    int j  = tid & 7;
    int l  = (tid >> 3) & 63;
    int blk = tid >> 9;            // ks*nbTot + nb
    int nb = blk % nbTot, ks = blk / nbTot;
    int k = ks * 32 + (l >> 4) * 8 + j;
    int n = nb * 16 + (l & 15);
    out[tid] = (k < Kreal) ? f2bf(W[(long)k * N + n]) : (short)0;
}

// ---------------- fused GEMM helper ----------------
template<int KSTEPS, int NBTOT>
__device__ __forceinline__ void mm_tile(const short* __restrict__ Ash, int ldab,
                                        const s16x8* __restrict__ Bp, int nb0,
                                        int r, int kg, f32x4 (&acc)[4][4]) {
    const int swz = (r & 7) << 4;
#pragma unroll
    for (int ks = 0; ks < KSTEPS; ++ks) {
        s16x8 a[4];
#pragma unroll
        for (int mi = 0; mi < 4; ++mi) {
            int row = mi * 16 + r;
            a[mi] = *(const s16x8*)((const char*)Ash + ((row * ldab + (ks * 32 + kg * 8) * 2) ^ swz));
        }
#pragma unroll
        for (int ni = 0; ni < 4; ++ni) {
            s16x8 b = Bp[(ks * NBTOT + nb0 + ni) * 64 + kg * 16 + r];
#pragma unroll
            for (int mi = 0; mi < 4; ++mi)
                acc[mi][ni] = __builtin_amdgcn_mfma_f32_16x16x32_bf16(a[mi], b, acc[mi][ni], 0, 0, 0);
        }
    }
}

// ---------------- layernorm stats (sum/sumsq -> mean/rstd in stat[]) ----------------
__device__ __forceinline__ void ln_stats(const f32x4 (&acc)[4][4], int tid,
                                         float red[64][4][2], float stat[64][2]) {
    int wave = tid >> 6, lane = tid & 63, r = lane & 15, kg = lane >> 4;
#pragma unroll
    for (int mi = 0; mi < 4; ++mi) {
#pragma unroll
        for (int j = 0; j < 4; ++j) {
            float s = 0.f, q = 0.f;
#pragma unroll
            for (int ni = 0; ni < 4; ++ni) { float v = acc[mi][ni][j]; s += v; q += v * v; }
#pragma unroll
            for (int m = 1; m < 16; m <<= 1) { s += __shfl_xor(s, m, 64); q += __shfl_xor(q, m, 64); }
            if (r == 0) { int row = mi * 16 + kg * 4 + j; red[row][wave][0] = s; red[row][wave][1] = q; }
        }
    }
    __syncthreads();
    if (tid < 64) {
        float s = red[tid][0][0] + red[tid][1][0] + red[tid][2][0] + red[tid][3][0];
        float q = red[tid][0][1] + red[tid][1][1] + red[tid][2][1] + red[tid][3][1];
        float mean = s * (1.f / 256.f);
        float var  = fmaxf(q * (1.f / 256.f) - mean * mean, 0.f);
        stat[tid][0] = mean;
        stat[tid][1] = rsqrtf(var + 1e-5f);
    }
    __syncthreads();
}

__device__ __forceinline__ void ln_apply(f32x4 (&acc)[4][4], const float* __restrict__ g,
                                         const float* __restrict__ bl,
                                         int wb, int r, int kg, float stat[64][2]) {
    float gv[4], bv[4];
#pragma unroll
    for (int ni = 0; ni < 4; ++ni) { gv[ni] = g[wb + ni * 16 + r]; bv[ni] = bl[wb + ni * 16 + r]; }
#pragma unroll
    for (int mi = 0; mi < 4; ++mi) {
#pragma unroll
        for (int j = 0; j < 4; ++j) {
            int row = mi * 16 + kg * 4 + j;
            float mean = stat[row][0], rstd = stat[row][1];
#pragma unroll
            for (int ni = 0; ni < 4; ++ni)
                acc[mi][ni][j] = (acc[mi][ni][j] - mean) * rstd * gv[ni] + bv[ni];
        }
    }
}

// ---------------- main fused kernel: 64 rows per block ----------------
__global__ __launch_bounds__(256, 2) void deq_main(
    const float* __restrict__ x, const float* __restrict__ z,
    const float* __restrict__ b_inp, const float* __restrict__ g_lni, const float* __restrict__ b_lni,
    const float* __restrict__ b1, const float* __restrict__ g_ln1, const float* __restrict__ b_ln1,
    const float* __restrict__ b2, const float* __restrict__ g_ln2, const float* __restrict__ b_ln2,
    const float* __restrict__ g_ln3, const float* __restrict__ b_ln3,
    const float* __restrict__ b_out,
    const s16x8* __restrict__ Wp1, const s16x8* __restrict__ Wp2,
    const s16x8* __restrict__ WpI, const s16x8* __restrict__ WpO,
    float* __restrict__ out_dx, float* __restrict__ out_z)
{
    __shared__ __align__(16) short A_sh[64 * 256];   // bf16, XOR-swizzled rows (stride 512B)
    __shared__ __align__(16) short X_sh[64 * 64];    // bf16, stride 128B, K-padded 48->64
    __shared__ float red_sh[64][4][2];
    __shared__ float stat_sh[64][2];

    const int tid = threadIdx.x;
    const int wave = tid >> 6, lane = tid & 63;
    const int r = lane & 15, kg = lane >> 4;
    const int swz = (r & 7) << 4;
    const long r0 = (long)blockIdx.x * 64;
    const int wb = wave * 64;                        // this wave's column slice

    // ---- stage z tile (64x256 f32 -> bf16 LDS, swizzled) ----
#pragma unroll
    for (int it = 0; it < 8; ++it) {
        int idx = it * 2048 + tid * 8;
        int row = idx >> 8, col = idx & 255;
        const float4* zp = (const float4*)(z + (r0 + row) * 256 + col);
        float4 f0 = zp[0], f1 = zp[1];
        s16x8 v;
        v[0] = f2bf(f0.x); v[1] = f2bf(f0.y); v[2] = f2bf(f0.z); v[3] = f2bf(f0.w);
        v[4] = f2bf(f1.x); v[5] = f2bf(f1.y); v[6] = f2bf(f1.z); v[7] = f2bf(f1.w);
        *(s16x8*)((char*)A_sh + ((row * 512 + col * 2) ^ ((row & 7) << 4))) = v;
    }
    // ---- stage x tile (64x48 -> padded 64x64) ----
#pragma unroll
    for (int i = 0; i < 12; ++i) {
        int idx = i * 256 + tid;
        int row = idx / 48, col = idx - row * 48;
        *(short*)((char*)X_sh + ((row * 128 + col * 2) ^ ((row & 7) << 4))) =
            f2bf(x[(r0 + row) * 48 + col]);
    }
    { // zero-pad cols 48..63 (8B per thread)
        int row = tid >> 2, c0 = 96 + (tid & 3) * 8;
        *(long long*)((char*)X_sh + ((row * 128 + c0) ^ ((row & 7) << 4))) = 0ll;
    }
    __syncthreads();

    // ---- xinp = LN(x @ W_inp + b_inp) ----
    f32x4 ax[4][4];
#pragma unroll
    for (int mi = 0; mi < 4; ++mi)
#pragma unroll
        for (int ni = 0; ni < 4; ++ni) ax[mi][ni] = (f32x4){0.f, 0.f, 0.f, 0.f};
    mm_tile<2, 16>(X_sh, 128, WpI, wave * 4, r, kg, ax);
    {
        float bb[4];
#pragma unroll
        for (int ni = 0; ni < 4; ++ni) bb[ni] = b_inp[wb + ni * 16 + r];
#pragma unroll
        for (int mi = 0; mi < 4; ++mi)
#pragma unroll
            for (int ni = 0; ni < 4; ++ni)
#pragma unroll
                for (int j = 0; j < 4; ++j) ax[mi][ni][j] += bb[ni];
    }
    ln_stats(ax, tid, red_sh, stat_sh);
    ln_apply(ax, g_lni, b_lni, wb, r, kg, stat_sh);   // ax = xinp (kept in regs)

    // ---- z1 = LN(relu(z @ W1 + b1)) ----
    f32x4 az[4][4];
#pragma unroll
    for (int mi = 0; mi < 4; ++mi)
#pragma unroll
        for (int ni = 0; ni < 4; ++ni) az[mi][ni] = (f32x4){0.f, 0.f, 0.f, 0.f};
    mm_tile<8, 16>(A_sh, 512, Wp1, wave * 4, r, kg, az);
    {
        float bb[4];
#pragma unroll
        for (int ni = 0; ni < 4; ++ni) bb[ni] = b1[wb + ni * 16 + r];
#pragma unroll
        for (int mi = 0; mi < 4; ++mi)
#pragma unroll
            for (int ni = 0; ni < 4; ++ni)
#pragma unroll
                for (int j = 0; j < 4; ++j) az[mi][ni][j] = fmaxf(az[mi][ni][j] + bb[ni], 0.f);
    }
    ln_stats(az, tid, red_sh, stat_sh);
    ln_apply(az, g_ln1, b_ln1, wb, r, kg, stat_sh);   // az = z1 (kept in regs)

    // write z1 (bf16) into A_sh for GEMM2  (all waves finished reading z: 2 syncs inside ln_stats)
#pragma unroll
    for (int mi = 0; mi < 4; ++mi)
#pragma unroll
        for (int j = 0; j < 4; ++j) {
            int row = mi * 16 + kg * 4 + j;
            int sw = (row & 7) << 4;
#pragma unroll
            for (int ni = 0; ni < 4; ++ni)
                *(short*)((char*)A_sh + ((row * 512 + (wb + ni * 16 + r) * 2) ^ sw)) = f2bf(az[mi][ni][j]);
        }
    __syncthreads();

    // ---- inner = LN(xinp + z1 @ W2 + b2)   (init MFMA C with xinp + b2) ----
    {
        float bb[4];
#pragma unroll
        for (int ni = 0; ni < 4; ++ni) bb[ni] = b2[wb + ni * 16 + r];
#pragma unroll
        for (int mi = 0; mi < 4; ++mi)
#pragma unroll
            for (int ni = 0; ni < 4; ++ni)
#pragma unroll
                for (int j = 0; j < 4; ++j) ax[mi][ni][j] += bb[ni];
    }
    mm_tile<8, 16>(A_sh, 512, Wp2, wave * 4, r, kg, ax);
    ln_stats(ax, tid, red_sh, stat_sh);
    ln_apply(ax, g_ln2, b_ln2, wb, r, kg, stat_sh);   // ax = inner

    // ---- z_out = LN(relu(z1 + inner)) ----
#pragma unroll
    for (int mi = 0; mi < 4; ++mi)
#pragma unroll
        for (int ni = 0; ni < 4; ++ni)
#pragma unroll
            for (int j = 0; j < 4; ++j) ax[mi][ni][j] = fmaxf(ax[mi][ni][j] + az[mi][ni][j], 0.f);
    ln_stats(ax, tid, red_sh, stat_sh);
    ln_apply(ax, g_ln3, b_ln3, wb, r, kg, stat_sh);   // ax = z_out

    // write z_out to global + into A_sh (bf16) for the output GEMM
#pragma unroll
    for (int mi = 0; mi < 4; ++mi)
#pragma unroll
        for (int j = 0; j < 4; ++j) {
            int row = mi * 16 + kg * 4 + j;
            int sw = (row & 7) << 4;
#pragma unroll
            for (int ni = 0; ni < 4; ++ni) {
                float v = ax[mi][ni][j];
                out_z[(r0 + row) * 256 + wb + ni * 16 + r] = v;
                *(short*)((char*)A_sh + ((row * 512 + (wb + ni * 16 + r) * 2) ^ sw)) = f2bf(v);
            }
        }
    __syncthreads();

    // ---- dx = z_out @ W_out + b_out   (each wave: 16 rows x 32 cols) ----
    f32x4 ao[2];
    ao[0] = (f32x4){0.f, 0.f, 0.f, 0.f};
    ao[1] = (f32x4){0.f, 0.f, 0.f, 0.f};
#pragma unroll
    for (int ks = 0; ks < 8; ++ks) {
        int row = wave * 16 + r;
        s16x8 a = *(const s16x8*)((const char*)A_sh + ((row * 512 + (ks * 32 + kg * 8) * 2) ^ swz));
#pragma unroll
        for (int ni = 0; ni < 2; ++ni) {
            s16x8 b = WpO[(ks * 2 + ni) * 64 + lane];
            ao[ni] = __builtin_amdgcn_mfma_f32_16x16x32_bf16(a, b, ao[ni], 0, 0, 0);
        }
    }
#pragma unroll
    for (int ni = 0; ni < 2; ++ni) {
        float bb = b_out[ni * 16 + r];
#pragma unroll
        for (int j = 0; j < 4; ++j)
            out_dx[(r0 + wave * 16 + kg * 4 + j) * 32 + ni * 16 + r] = ao[ni][j] + bb;
    }
}

extern "C" void kernel_launch(void* const* d_in, const int* in_sizes, int n_in,
                              void* d_out, int out_size, void* d_ws, size_t ws_size,
                              hipStream_t stream) {
    const float* x      = (const float*)d_in[0];
    const float* z      = (const float*)d_in[1];
    const float* W_inp  = (const float*)d_in[2];
    const float* b_inp  = (const float*)d_in[3];
    const float* g_lni  = (const float*)d_in[4];
    const float* b_lni  = (const float*)d_in[5];
    const float* W1     = (const float*)d_in[6];
    const float* b1     = (const float*)d_in[7];
    const float* g_ln1  = (const float*)d_in[8];
    const float* b_ln1  = (const float*)d_in[9];
    const float* W2     = (const float*)d_in[10];
    const float* b2     = (const float*)d_in[11];
    const float* g_ln2  = (const float*)d_in[12];
    const float* b_ln2  = (const float*)d_in[13];
    const float* g_ln3  = (const float*)d_in[14];
    const float* b_ln3  = (const float*)d_in[15];
    const float* W_out  = (const float*)d_in[16];
    const float* b_out  = (const float*)d_in[17];

    short* Wp1 = (short*)d_ws;            // 8*16*64*8  = 65536 bf16
    short* Wp2 = Wp1 + 65536;             // 65536
    short* WpI = Wp2 + 65536;             // 2*16*64*8  = 16384
    short* WpO = WpI + 16384;             // 8*2*64*8   = 8192

    pack_w<<<256, 256, 0, stream>>>(W1,    Wp1, 256, 256, 16, 65536);
    pack_w<<<256, 256, 0, stream>>>(W2,    Wp2, 256, 256, 16, 65536);
    pack_w<<< 64, 256, 0, stream>>>(W_inp, WpI,  48, 256, 16, 16384);
    pack_w<<< 32, 256, 0, stream>>>(W_out, WpO, 256,  32,  2,  8192);

    const long B = 262144;
    float* out_dx = (float*)d_out;
    float* out_z  = out_dx + B * 32;
    deq_main<<<B / 64, 256, 0, stream>>>(x, z, b_inp, g_lni, b_lni,
                                         b1, g_ln1, b_ln1, b2, g_ln2, b_ln2,
                                         g_ln3, b_ln3, b_out,
                                         (const s16x8*)Wp1, (const s16x8*)Wp2,
                                         (const s16x8*)WpI, (const s16x8*)WpO,
                                         out_dx, out_z);
}